// Round 2
// baseline (659.469 us; speedup 1.0000x reference)
//
#include <hip/hip_runtime.h>
#include <math.h>

#define NT 16384   // tokens
#define HD 4096    // hidden dim
#define NE 64      // experts
#define TT 64      // tokens per block
#define KW 1024    // K-slice per wave (4 waves x 1024 = 4096)
#define DC 32      // d per chunk (128B per token row = one cache line)
#define NCHW (KW / DC)   // 32 chunks per wave
#define SXS 68     // sX row stride (floats): 68%32=4 -> 2-way write alias (free), 16B-aligned rows
#define SLS 65     // score stride: 65%32=1 -> conflict-free column scans
#define GAP_THRESH 4e-5f   // ~80 sigma of fp32 gap noise

__device__ __forceinline__ float fsig(float z) { return 1.0f / (1.0f + expf(-z)); }
__device__ __forceinline__ double dsig(double z) { return 1.0 / (1.0 + exp(-z)); }

// Main pass: fp32, LDS-traffic-optimized. 256 blocks x 256 threads (1 block/CU).
// Each of the 4 waves owns a private K-slice of 1024 and a private double-buffered
// LDS region -> ZERO barriers in the K-loop (in-wave DS ordering suffices).
// Thread tile 8 tok x 8 exp = 64 FMA per 64B of LDS reads (1 B/FMA, was 3).
// Deterministic cross-wave reduction ((w0+w1)+w2)+w3 through sL, then top-9 +
// near-tie flagging for exact fp64 re-resolution.
__global__ __launch_bounds__(256, 1) void moe_gate_f32(
    const float* __restrict__ X, const float* __restrict__ Wg,
    const float* __restrict__ bias, float* __restrict__ out,
    unsigned int* __restrict__ nflag, int* __restrict__ flags) {
  __shared__ float sX[4][2][DC][SXS];  // per-wave dbuf, x transposed [d][token]
  __shared__ float sW[4][2][DC][NE];   // per-wave dbuf, W natural [d][expert]
  __shared__ float sL[TT][SLS];        // score matrix [token][expert]
  __shared__ float sB[NE];

  const int tid  = threadIdx.x;
  const int wv   = tid >> 6;     // wave 0..3 -> K-slice [wv*1024, wv*1024+1024)
  const int ln   = tid & 63;     // lane
  const int tok0 = blockIdx.x * TT;
  const int tr8  = (ln & 7) * 8; // tokens tr8..tr8+7
  const int tc8  = (ln >> 3) * 8;// experts tc8..tc8+7

  if (tid < NE) sB[tid] = bias[tid];

  float acc[8][8];
#pragma unroll
  for (int i = 0; i < 8; ++i)
#pragma unroll
    for (int j = 0; j < 8; ++j) acc[i][j] = 0.0f;

  const float* xbase = X + (size_t)(tok0 + ln) * HD + wv * KW;
  const float* wbase = Wg + (size_t)(wv * KW) * NE;

  float4 xr[8], wr[8];
  // prologue: load + stage chunk 0 into buf 0 (wave-local, no barrier)
#pragma unroll
  for (int s = 0; s < 8; ++s) xr[s] = *(const float4*)(xbase + s * 4);
#pragma unroll
  for (int s = 0; s < 8; ++s) wr[s] = *(const float4*)(wbase + (ln + 64 * s) * 4);
#pragma unroll
  for (int s = 0; s < 8; ++s) {
    const int d0 = s * 4;
    sX[wv][0][d0 + 0][ln] = xr[s].x;
    sX[wv][0][d0 + 1][ln] = xr[s].y;
    sX[wv][0][d0 + 2][ln] = xr[s].z;
    sX[wv][0][d0 + 3][ln] = xr[s].w;
    *(float4*)&sW[wv][0][(ln >> 4) + 4 * s][(ln & 15) * 4] = wr[s];
  }

  for (int c = 0; c < NCHW; ++c) {
    const int pb = c & 1;
    if (c + 1 < NCHW) {  // prefetch next chunk; latency hides under compute
      const float* xp = xbase + (c + 1) * DC;
      const float* wp = wbase + (size_t)((c + 1) * DC) * NE;
#pragma unroll
      for (int s = 0; s < 8; ++s) xr[s] = *(const float4*)(xp + s * 4);
#pragma unroll
      for (int s = 0; s < 8; ++s) wr[s] = *(const float4*)(wp + (ln + 64 * s) * 4);
    }
#pragma unroll 8
    for (int dd = 0; dd < DC; ++dd) {
      const float4 xa = *(const float4*)&sX[wv][pb][dd][tr8];
      const float4 xb = *(const float4*)&sX[wv][pb][dd][tr8 + 4];
      const float4 wa = *(const float4*)&sW[wv][pb][dd][tc8];
      const float4 wb = *(const float4*)&sW[wv][pb][dd][tc8 + 4];
      const float xv[8] = {xa.x, xa.y, xa.z, xa.w, xb.x, xb.y, xb.z, xb.w};
      const float wf[8] = {wa.x, wa.y, wa.z, wa.w, wb.x, wb.y, wb.z, wb.w};
#pragma unroll
      for (int i = 0; i < 8; ++i)
#pragma unroll
        for (int j = 0; j < 8; ++j) acc[i][j] += xv[i] * wf[j];
    }
    if (c + 1 < NCHW) {  // stage prefetched chunk into the other buffer
      const int nb = pb ^ 1;
#pragma unroll
      for (int s = 0; s < 8; ++s) {
        const int d0 = s * 4;
        sX[wv][nb][d0 + 0][ln] = xr[s].x;
        sX[wv][nb][d0 + 1][ln] = xr[s].y;
        sX[wv][nb][d0 + 2][ln] = xr[s].z;
        sX[wv][nb][d0 + 3][ln] = xr[s].w;
        *(float4*)&sW[wv][nb][(ln >> 4) + 4 * s][(ln & 15) * 4] = wr[s];
      }
    }
  }

  // deterministic cross-wave reduction into sL: pass w adds wave w's partials.
  // j staggered by token-group -> 2-way bank alias (free). Sigmoid on last pass.
  __syncthreads();
  for (int w = 0; w < 4; ++w) {
    if (wv == w) {
#pragma unroll
      for (int i = 0; i < 8; ++i)
#pragma unroll
        for (int jj = 0; jj < 8; ++jj) {
          const int j = (jj + (ln & 7)) & 7;
          float* p = &sL[tr8 + i][tc8 + j];
          float v = (w == 0) ? acc[i][j] : (*p + acc[i][j]);
          *p = (w == 3) ? fsig(v) : v;
        }
    }
    __syncthreads();
  }

  // one lane per token: branchless bubble top-9; flag near-ties for fp64 pass.
  if (tid < TT) {
    const int t = tid;
    float bsc[9]; int bix[9];
#pragma unroll
    for (int r = 0; r < 9; ++r) { bsc[r] = -INFINITY; bix[r] = 0; }
    for (int e = 0; e < NE; ++e) {
      float cb = sL[t][e] + sB[e];
      int   ci = e;
#pragma unroll
      for (int r = 0; r < 9; ++r) {
        const bool sw = cb > bsc[r];
        const float tb = bsc[r]; const int ti = bix[r];
        bsc[r] = sw ? cb : tb;  bix[r] = sw ? ci : ti;
        cb     = sw ? tb : cb;  ci     = sw ? ti : ci;
      }
    }
    float mg = bsc[0] - bsc[1];
#pragma unroll
    for (int r = 1; r < 8; ++r) mg = fminf(mg, bsc[r] - bsc[r + 1]);

    float us[8]; float sum = 1e-20f;
#pragma unroll
    for (int r = 0; r < 8; ++r) { us[r] = sL[t][bix[r]]; sum += us[r]; }
    const float sc = 2.5f / sum;
    const size_t o = (size_t)(tok0 + t) * 8;
    float4 i0 = {(float)bix[0], (float)bix[1], (float)bix[2], (float)bix[3]};
    float4 i1 = {(float)bix[4], (float)bix[5], (float)bix[6], (float)bix[7]};
    *(float4*)(out + o)     = i0;
    *(float4*)(out + o + 4) = i1;
    float* ow = out + (size_t)NT * 8;
    float4 w0 = {us[0] * sc, us[1] * sc, us[2] * sc, us[3] * sc};
    float4 w1 = {us[4] * sc, us[5] * sc, us[6] * sc, us[7] * sc};
    *(float4*)(ow + o)     = w0;
    *(float4*)(ow + o + 4) = w1;

    if (!(mg > GAP_THRESH)) {  // NaN-safe
      const unsigned int p = atomicAdd(nflag, 1u);
      if (p < NT) flags[p] = tok0 + t;
    }
  }
}

// Exact fp64 fallback: ONE WAVE per flagged token. lane = expert; x broadcast
// (single txn, L1-hot), W columns coalesced 256B. Fixed-order 4-chain sum ->
// deterministic. No __syncthreads (waves take different trip counts).
__global__ __launch_bounds__(256, 1) void moe_gate_fix(
    const float* __restrict__ X, const float* __restrict__ Wg,
    const float* __restrict__ bias, float* __restrict__ out,
    const unsigned int* __restrict__ nflag, const int* __restrict__ flags) {
  __shared__ double sS[4][NE];
  const int tid = threadIdx.x, wv = tid >> 6, ln = tid & 63;
  unsigned int n = *nflag;
  if (n > NT) n = NT;
  const unsigned int wid = blockIdx.x * 4 + wv;
  const unsigned int wstride = gridDim.x * 4;

  for (unsigned int w = wid; w < n; w += wstride) {
    const int t = flags[w];
    const float* xp = X + (size_t)t * HD;
    const float* wp = Wg + ln;
    double c0 = 0.0, c1 = 0.0, c2 = 0.0, c3 = 0.0;
    for (int d = 0; d < HD; d += 4) {
      const float4 x4 = *(const float4*)(xp + d);
      const float w0 = wp[(size_t)(d + 0) * NE];
      const float w1 = wp[(size_t)(d + 1) * NE];
      const float w2 = wp[(size_t)(d + 2) * NE];
      const float w3 = wp[(size_t)(d + 3) * NE];
      c0 += (double)x4.x * (double)w0;
      c1 += (double)x4.y * (double)w1;
      c2 += (double)x4.z * (double)w2;
      c3 += (double)x4.w * (double)w3;
    }
    sS[wv][ln] = dsig(((c0 + c1) + c2) + c3);  // in-wave DS ordering: visible below

    if (ln == 0) {
      double bsc[8]; int bix[8];
#pragma unroll
      for (int r = 0; r < 8; ++r) { bsc[r] = -INFINITY; bix[r] = 0; }
      for (int e = 0; e < NE; ++e) {
        double cb = sS[wv][e] + (double)bias[e];
        int   ci = e;
#pragma unroll
        for (int r = 0; r < 8; ++r) {
          const bool sw = cb > bsc[r];
          const double tb = bsc[r]; const int ti = bix[r];
          bsc[r] = sw ? cb : tb;  bix[r] = sw ? ci : ti;
          cb     = sw ? tb : cb;  ci     = sw ? ti : ci;
        }
      }
      double us[8]; double sum = 1e-20;
#pragma unroll
      for (int r = 0; r < 8; ++r) { us[r] = sS[wv][bix[r]]; sum += us[r]; }
      const double sc = 2.5 / sum;
      const size_t o = (size_t)t * 8;
      float4 i0 = {(float)bix[0], (float)bix[1], (float)bix[2], (float)bix[3]};
      float4 i1 = {(float)bix[4], (float)bix[5], (float)bix[6], (float)bix[7]};
      *(float4*)(out + o)     = i0;
      *(float4*)(out + o + 4) = i1;
      float* ow = out + (size_t)NT * 8;
      float4 w0 = {(float)(us[0] * sc), (float)(us[1] * sc),
                   (float)(us[2] * sc), (float)(us[3] * sc)};
      float4 w1 = {(float)(us[4] * sc), (float)(us[5] * sc),
                   (float)(us[6] * sc), (float)(us[7] * sc)};
      *(float4*)(ow + o)     = w0;
      *(float4*)(ow + o + 4) = w1;
    }
  }
}

extern "C" void kernel_launch(void* const* d_in, const int* in_sizes, int n_in,
                              void* d_out, int out_size, void* d_ws, size_t ws_size,
                              hipStream_t stream) {
  const float* X  = (const float*)d_in[0];
  const float* Wg = (const float*)d_in[1];
  const float* b  = (const float*)d_in[2];
  float* out = (float*)d_out;
  unsigned int* nflag = (unsigned int*)d_ws;
  int* flags = (int*)((char*)d_ws + 64);
  hipMemsetAsync(d_ws, 0, 64, stream);
  hipLaunchKernelGGL(moe_gate_f32, dim3(NT / TT), dim3(256), 0, stream,
                     X, Wg, b, out, nflag, flags);
  hipLaunchKernelGGL(moe_gate_fix, dim3(256), dim3(256), 0, stream,
                     X, Wg, b, out, nflag, flags);
}

// Round 4
// 488.048 us; speedup vs baseline: 1.3512x; 1.3512x over previous
//
#include <hip/hip_runtime.h>
#include <math.h>

#define NT 16384   // tokens
#define HD 4096    // hidden dim
#define NE 64      // experts
#define GAP_THRESH 4e-5f   // 30 sigma of split-bf16 gap noise (validated at fp32 noise level)

typedef __bf16 bf16x8 __attribute__((ext_vector_type(8)));
typedef float f32x4 __attribute__((ext_vector_type(4)));
typedef unsigned int u32x4 __attribute__((ext_vector_type(4)));

// W pre-split into bf16 hi/lo MFMA B-fragments: [hi: 262144][lo: 262144] ushorts (1 MB).
// Element j of lane l for (kb, nf) = W[kb*32 + (l>>4)*8 + j][nf*16 + (l&15)],
// stored at g_Wp[kb*2048 + nf*512 + l*8 + j].
__device__ __attribute__((aligned(16))) unsigned short g_Wp[524288];

__device__ __forceinline__ float fsig(float z) { return 1.0f / (1.0f + expf(-z)); }
__device__ __forceinline__ double dsig(double z) { return 1.0 / (1.0 + exp(-z)); }

__device__ __forceinline__ f32x4 mfma16(bf16x8 a, bf16x8 b, f32x4 c) {
  return __builtin_amdgcn_mfma_f32_16x16x32_bf16(a, b, c, 0, 0, 0);
}

// bit-level f32 -> bf16 RNE (exact for finite inputs; data is Gaussian, no NaN/inf)
__device__ __forceinline__ unsigned bf16_rne(float f) {
  const unsigned u = __builtin_bit_cast(unsigned, f);
  return (u + 0x7FFFu + ((u >> 16) & 1u)) >> 16;
}

// split f32 pair -> packed bf16 hi and bf16 lo (lo = rne(x - hi)); x-hi is exact in
// fp32 (hi agrees with x in the leading 8 mantissa bits), so residual <= 2^-18 |x|.
__device__ __forceinline__ void split2(float f0, float f1, unsigned& hi, unsigned& lo) {
  const unsigned h0 = bf16_rne(f0), h1 = bf16_rne(f1);
  const float hf0 = __builtin_bit_cast(float, h0 << 16);
  const float hf1 = __builtin_bit_cast(float, h1 << 16);
  const unsigned l0 = bf16_rne(f0 - hf0), l1 = bf16_rne(f1 - hf1);
  hi = h0 | (h1 << 16);
  lo = l0 | (l1 << 16);
}

// One-time (per launch) W split+permute. 128 blocks x 256 threads = 32768 frags.
__global__ __launch_bounds__(256) void prep_w(const float* __restrict__ Wg) {
  const int g  = blockIdx.x * 256 + threadIdx.x;  // = kb*256 + nf*64 + l
  const int l  = g & 63;
  const int nf = (g >> 6) & 3;
  const int kb = g >> 8;
  const int d0 = kb * 32 + (l >> 4) * 8;
  const int e  = nf * 16 + (l & 15);
  u32x4 hi, lo;
#pragma unroll
  for (int p = 0; p < 4; ++p) {
    const float f0 = Wg[(size_t)(d0 + 2 * p) * NE + e];
    const float f1 = Wg[(size_t)(d0 + 2 * p + 1) * NE + e];
    unsigned th, tl;
    split2(f0, f1, th, tl);
    hi[p] = th; lo[p] = tl;
  }
  *(u32x4*)(g_Wp + (size_t)g * 8) = hi;
  *(u32x4*)(g_Wp + 262144 + (size_t)g * 8) = lo;
}

// Main pass: split-bf16 MFMA GEMM, HBM-bound on X. 512 blocks x 256 threads;
// 4 waves = 2 token-groups x 2 K-halves (16 tok x 64 exp x K=2048 each) -> 2 waves/SIMD.
// No LDS staging: A streams global->reg->cvt->frag (nontemporal, no reuse);
// B-frags load contiguous 16B/lane from L2-resident g_Wp. 4 cross-products give
// fp32-class accuracy; near-ties flagged for exact fp64 re-resolution.
__global__ __launch_bounds__(256, 2) void moe_gate_f32(
    const float* __restrict__ X, const float* __restrict__ bias,
    float* __restrict__ out, unsigned int* __restrict__ nflag,
    int* __restrict__ flags) {
  __shared__ float sL[32][65];   // sigmoid scores [token][expert]
  __shared__ float sB[NE];

  const int tid = threadIdx.x;
  const int l   = tid & 63;
  const int wv  = tid >> 6;
  const int tg  = wv >> 1;   // token group: tokens [tg*16, tg*16+16)
  const int kh  = wv & 1;    // K half: [kh*2048, kh*2048+2048)
  const int tok0 = blockIdx.x * 32;

  if (tid < NE) sB[tid] = bias[tid];

  // A: lane l holds row (l&15), k = (l>>4)*8 + j  (8 consecutive fp32)
  const float* xp = X + (size_t)(tok0 + tg * 16 + (l & 15)) * HD + kh * 2048 + (l >> 4) * 8;
  const unsigned short* wp = g_Wp + kh * 131072 + l * 8;

  f32x4 accm[4], accc[4];
#pragma unroll
  for (int nf = 0; nf < 4; ++nf) {
    accm[nf] = f32x4{0.f, 0.f, 0.f, 0.f};
    accc[nf] = f32x4{0.f, 0.f, 0.f, 0.f};
  }

  // software pipeline: one K-step (32) lookahead in registers
  f32x4 a0c = __builtin_nontemporal_load((const f32x4*)xp);
  f32x4 a1c = __builtin_nontemporal_load((const f32x4*)(xp + 4));
  u32x4 bhc[4], blc[4], bhn[4], bln[4];
#pragma unroll
  for (int nf = 0; nf < 4; ++nf) {
    bhc[nf] = *(const u32x4*)(wp + nf * 512);
    blc[nf] = *(const u32x4*)(wp + 262144 + nf * 512);
  }
  f32x4 a0n, a1n;

  for (int c = 0; c < 64; ++c) {
    if (c < 63) {
      const float* xn = xp + (c + 1) * 32;
      a0n = __builtin_nontemporal_load((const f32x4*)xn);
      a1n = __builtin_nontemporal_load((const f32x4*)(xn + 4));
      const unsigned short* wn = wp + (size_t)(c + 1) * 2048;
#pragma unroll
      for (int nf = 0; nf < 4; ++nf) {
        bhn[nf] = *(const u32x4*)(wn + nf * 512);
        bln[nf] = *(const u32x4*)(wn + 262144 + nf * 512);
      }
    }
    // convert A to split-bf16 fragments
    u32x4 ahu, alu;
    {
      unsigned th, tl;
      split2(a0c[0], a0c[1], th, tl); ahu[0] = th; alu[0] = tl;
      split2(a0c[2], a0c[3], th, tl); ahu[1] = th; alu[1] = tl;
      split2(a1c[0], a1c[1], th, tl); ahu[2] = th; alu[2] = tl;
      split2(a1c[2], a1c[3], th, tl); ahu[3] = th; alu[3] = tl;
    }
    const bf16x8 ah = __builtin_bit_cast(bf16x8, ahu);
    const bf16x8 al = __builtin_bit_cast(bf16x8, alu);
#pragma unroll
    for (int nf = 0; nf < 4; ++nf) {
      const bf16x8 bh = __builtin_bit_cast(bf16x8, bhc[nf]);
      const bf16x8 bl = __builtin_bit_cast(bf16x8, blc[nf]);
      accm[nf] = mfma16(ah, bh, accm[nf]);   // main product
      accc[nf] = mfma16(ah, bl, accc[nf]);   // cross terms
      accc[nf] = mfma16(al, bh, accc[nf]);
      accc[nf] = mfma16(al, bl, accc[nf]);
    }
    if (c < 63) {
      a0c = a0n; a1c = a1n;
#pragma unroll
      for (int nf = 0; nf < 4; ++nf) { bhc[nf] = bhn[nf]; blc[nf] = bln[nf]; }
    }
  }

  // C layout (m89-verified): expert = nf*16 + (l&15), token = tg*16 + (l>>4)*4 + r.
  // Deterministic K-half combine: logit = (m0+c0) + (m1+c1); sigmoid on second pass.
  if (kh == 0) {
#pragma unroll
    for (int nf = 0; nf < 4; ++nf)
#pragma unroll
      for (int r = 0; r < 4; ++r)
        sL[tg * 16 + (l >> 4) * 4 + r][nf * 16 + (l & 15)] = accm[nf][r] + accc[nf][r];
  }
  __syncthreads();
  if (kh == 1) {
#pragma unroll
    for (int nf = 0; nf < 4; ++nf)
#pragma unroll
      for (int r = 0; r < 4; ++r) {
        const int t = tg * 16 + (l >> 4) * 4 + r, e = nf * 16 + (l & 15);
        sL[t][e] = fsig(sL[t][e] + (accm[nf][r] + accc[nf][r]));
      }
  }
  __syncthreads();

  // one lane per token: branchless bubble top-9; flag near-ties for the fp64 pass.
  if (tid < 32) {
    const int t = tid;
    float bsc[9]; int bix[9];
#pragma unroll
    for (int r = 0; r < 9; ++r) { bsc[r] = -INFINITY; bix[r] = 0; }
    for (int e = 0; e < NE; ++e) {
      float cb = sL[t][e] + sB[e];
      int   ci = e;
#pragma unroll
      for (int r = 0; r < 9; ++r) {
        const bool sw = cb > bsc[r];
        const float tb = bsc[r]; const int ti = bix[r];
        bsc[r] = sw ? cb : tb;  bix[r] = sw ? ci : ti;
        cb     = sw ? tb : cb;  ci     = sw ? ti : ci;
      }
    }
    float mg = bsc[0] - bsc[1];
#pragma unroll
    for (int r = 1; r < 8; ++r) mg = fminf(mg, bsc[r] - bsc[r + 1]);

    float us[8]; float sum = 1e-20f;
#pragma unroll
    for (int r = 0; r < 8; ++r) { us[r] = sL[t][bix[r]]; sum += us[r]; }
    const float sc = 2.5f / sum;
    const size_t o = (size_t)(tok0 + t) * 8;
    float4 i0 = {(float)bix[0], (float)bix[1], (float)bix[2], (float)bix[3]};
    float4 i1 = {(float)bix[4], (float)bix[5], (float)bix[6], (float)bix[7]};
    *(float4*)(out + o)     = i0;
    *(float4*)(out + o + 4) = i1;
    float* ow = out + (size_t)NT * 8;
    float4 w0 = {us[0] * sc, us[1] * sc, us[2] * sc, us[3] * sc};
    float4 w1 = {us[4] * sc, us[5] * sc, us[6] * sc, us[7] * sc};
    *(float4*)(ow + o)     = w0;
    *(float4*)(ow + o + 4) = w1;

    if (!(mg > GAP_THRESH)) {  // NaN-safe
      const unsigned int p = atomicAdd(nflag, 1u);
      if (p < NT) flags[p] = tok0 + t;
    }
  }
}

// Exact fp64 fallback, throughput-oriented: 8 flagged tokens per 512-thread block.
// Thread (e = tid&63, q = tid>>6): K-slice of 512; each coalesced W read feeds
// 16 fp64 FMAs (8 tokens x 2 d). Deterministic ordered reduction (((q0+q1)+..)+q7).
#define FB 8
__global__ __launch_bounds__(512) void moe_gate_fix(
    const float* __restrict__ X, const float* __restrict__ Wg,
    const float* __restrict__ bias, float* __restrict__ out,
    const unsigned int* __restrict__ nflag, const int* __restrict__ flags) {
  __shared__ float  sx[FB][1024];     // 32 KB X chunk (8 rows x 1024 d)
  __shared__ double sP[8][FB][NE];    // 32 KB partials [q][tok][expert]
  __shared__ double sS[FB][NE];       // fp64 sigmoid scores
  __shared__ int    stok[FB];

  const int tid = threadIdx.x;
  const int e = tid & 63, q = tid >> 6;
  unsigned int n = *nflag;
  if (n > NT) n = NT;

  for (unsigned int base = blockIdx.x * FB; base < n; base += gridDim.x * FB) {
    const int cnt = (int)((n - base < (unsigned)FB) ? (n - base) : (unsigned)FB);
    __syncthreads();  // prev iter's stok/sS readers done
    if (tid < FB) stok[tid] = flags[base + ((tid < cnt) ? tid : 0)];
    double acc[FB];
#pragma unroll
    for (int t = 0; t < FB; ++t) acc[t] = 0.0;

    for (int ch = 0; ch < 4; ++ch) {
      __syncthreads();  // sx reuse guard; makes stok visible on ch==0
#pragma unroll
      for (int s = 0; s < 4; ++s) {
        const int idx = tid + 512 * s;          // 2048 float4 slots
        const int r = idx >> 8, c4 = (idx & 255) * 4;
        *(float4*)&sx[r][c4] =
            *(const float4*)(X + (size_t)stok[r] * HD + ch * 1024 + c4);
      }
      __syncthreads();
      const int db = ch * 1024 + q * 128;
#pragma unroll 4
      for (int dd = 0; dd < 128; dd += 2) {
        const double w0 = (double)Wg[(size_t)(db + dd) * NE + e];
        const double w1 = (double)Wg[(size_t)(db + dd + 1) * NE + e];
#pragma unroll
        for (int t = 0; t < FB; ++t) {
          const float2 xv = *(const float2*)&sx[t][q * 128 + dd];
          acc[t] += (double)xv.x * w0;
          acc[t] += (double)xv.y * w1;
        }
      }
    }
#pragma unroll
    for (int t = 0; t < FB; ++t) sP[q][t][e] = acc[t];
    __syncthreads();
    if (tid < FB * NE) {
      const int t = tid >> 6;
      double s = 0.0;
#pragma unroll
      for (int qq = 0; qq < 8; ++qq) s += sP[qq][t][e];  // fixed ascending order
      sS[t][e] = dsig(s);
    }
    __syncthreads();
    if (tid < cnt) {
      const int t = tid;
      double bsc[8]; int bix[8];
#pragma unroll
      for (int r = 0; r < 8; ++r) { bsc[r] = -INFINITY; bix[r] = 0; }
      for (int ee = 0; ee < NE; ++ee) {
        double cb = sS[t][ee] + (double)bias[ee];
        int   ci = ee;
#pragma unroll
        for (int r = 0; r < 8; ++r) {
          const bool sw = cb > bsc[r];
          const double tb = bsc[r]; const int ti = bix[r];
          bsc[r] = sw ? cb : tb;  bix[r] = sw ? ci : ti;
          cb     = sw ? tb : cb;  ci     = sw ? ti : ci;
        }
      }
      double us[8]; double sum = 1e-20;
#pragma unroll
      for (int r = 0; r < 8; ++r) { us[r] = sS[t][bix[r]]; sum += us[r]; }
      const double sc = 2.5 / sum;
      const size_t o = (size_t)stok[t] * 8;
      float4 i0 = {(float)bix[0], (float)bix[1], (float)bix[2], (float)bix[3]};
      float4 i1 = {(float)bix[4], (float)bix[5], (float)bix[6], (float)bix[7]};
      *(float4*)(out + o)     = i0;
      *(float4*)(out + o + 4) = i1;
      float* ow = out + (size_t)NT * 8;
      float4 w0 = {(float)(us[0] * sc), (float)(us[1] * sc),
                   (float)(us[2] * sc), (float)(us[3] * sc)};
      float4 w1 = {(float)(us[4] * sc), (float)(us[5] * sc),
                   (float)(us[6] * sc), (float)(us[7] * sc)};
      *(float4*)(ow + o)     = w0;
      *(float4*)(ow + o + 4) = w1;
    }
  }
}

extern "C" void kernel_launch(void* const* d_in, const int* in_sizes, int n_in,
                              void* d_out, int out_size, void* d_ws, size_t ws_size,
                              hipStream_t stream) {
  const float* X  = (const float*)d_in[0];
  const float* Wg = (const float*)d_in[1];
  const float* b  = (const float*)d_in[2];
  float* out = (float*)d_out;
  unsigned int* nflag = (unsigned int*)d_ws;
  int* flags = (int*)((char*)d_ws + 64);
  (void)hipMemsetAsync(d_ws, 0, 64, stream);
  hipLaunchKernelGGL(prep_w, dim3(128), dim3(256), 0, stream, Wg);
  hipLaunchKernelGGL(moe_gate_f32, dim3(NT / 32), dim3(256), 0, stream,
                     X, b, out, nflag, flags);
  hipLaunchKernelGGL(moe_gate_fix, dim3(256), dim3(512), 0, stream,
                     X, Wg, b, out, nflag, flags);
}